// Round 11
// baseline (248.033 us; speedup 1.0000x reference)
//
#include <hip/hip_runtime.h>
#include <cstdint>
#include <cstddef>

typedef unsigned short u16;
typedef unsigned int u32;
typedef __attribute__((ext_vector_type(8))) short bf16x8;
typedef __attribute__((ext_vector_type(4))) float f32x4;
typedef __attribute__((ext_vector_type(16))) float f32x16;

__device__ __forceinline__ u16 f2bf(float f) {
  union { float f; unsigned int u; } v; v.f = f;
  unsigned int r = v.u + 0x7fffu + ((v.u >> 16) & 1u);
  return (u16)(r >> 16);
}

__device__ __forceinline__ u32 pack_bf_trunc(float hi, float lo) {
#if __has_builtin(__builtin_amdgcn_perm)
  return __builtin_amdgcn_perm(__float_as_uint(hi), __float_as_uint(lo), 0x07060302u);
#else
  return (__float_as_uint(hi) & 0xffff0000u) | (__float_as_uint(lo) >> 16);
#endif
}

__device__ __forceinline__ u32 cvt_pk_bf16(float lo, float hi) {
  u32 r;
  asm("v_cvt_pk_bf16_f32 %0, %1, %2" : "=v"(r) : "v"(lo), "v"(hi));
  return r;   // .lo16 = bf16(lo), .hi16 = bf16(hi), RNE — matches f2bf
}

__device__ __forceinline__ void glds16(const void* g, void* l) {
  __builtin_amdgcn_global_load_lds(
      (const __attribute__((address_space(1))) unsigned int*)g,
      (__attribute__((address_space(3))) unsigned int*)l, 16, 0, 0);
}

__device__ __forceinline__ f32x4 fzero4() { f32x4 z = {0.f, 0.f, 0.f, 0.f}; return z; }
__device__ __forceinline__ f32x16 fzero16() {
  f32x16 z;
  #pragma unroll
  for (int i = 0; i < 16; ++i) z[i] = 0.f;
  return z;
}

// ---------------- prep: transpose-convert weights only (x/y cvt folded into gemm) ----------------
__global__ __launch_bounds__(256)
void prep_w_kernel(const float* __restrict__ Wq, const float* __restrict__ Wk,
                   const float* __restrict__ Wv, u16* __restrict__ wt) {
  __shared__ float tile[32][33];
  int t = blockIdx.x;                       // 0..1535
  const float* in; u16* out; int N, tn;
  if (t < 256)      { in = Wq; out = wt;              N = 256;  tn = t; }
  else if (t < 512) { in = Wk; out = wt + 256 * 1024; N = 256;  tn = t - 256; }
  else              { in = Wv; out = wt + 512 * 1024; N = 1024; tn = t - 512; }
  int ntiles = N >> 5;
  int n0 = (tn % ntiles) * 32, k0 = (tn / ntiles) * 32;
  int tx = threadIdx.x & 31, ty = threadIdx.x >> 5;
  #pragma unroll
  for (int j = ty; j < 32; j += 8) tile[j][tx] = in[(size_t)(k0 + j) * N + n0 + tx];
  __syncthreads();
  #pragma unroll
  for (int j = ty; j < 32; j += 8) out[(size_t)(n0 + j) * 1024 + k0 + tx] = f2bf(tile[tx][j]);
}

// ---------------- fused projection GEMM (BK=64, dbuf-B prefetch-during-compute, 3 blocks/CU) ----
// Per K-step: cvt+ds_write A(k) [regs landed during compute(k-1)]; barrier;
// ISSUE B(k+1) glds + A(k+1) loads; compute(k); barrier (drain lands AFTER compute -> hidden).
// NOTE: stageB/loadA take ELEMENT offsets (k0 = tile*64) — round-10 bug was passing tile idx.
// out tiles over [8192][1536]: cols 0-255 -> fb (Q), 256-511 -> gb (K), 512-1535 -> ht (V).
__global__ __launch_bounds__(256, 3)
void gemm_all_kernel(const float* __restrict__ x, const float* __restrict__ y,
                     const u16* __restrict__ wt,
                     const float* __restrict__ bq, const float* __restrict__ bk,
                     const float* __restrict__ bv,
                     u16* __restrict__ fb, u16* __restrict__ gb, u16* __restrict__ ht) {
  __shared__ __align__(16) u16 ls[24576];   // 48 KB: lA 16KB + lB dbuf 2x16KB; epilogue reuses
  u16* lA  = ls;           // 8192 u16: A tile [kc=8][row=128][8] bf16, rows XOR-swizzled
  u16* lB0 = ls + 8192;    // 8192 u16: B tile [kc=8][col=128][8]
  u16* lB1 = ls + 16384;
  const int tid = threadIdx.x, lane = tid & 63;
  const int quad = lane >> 4, l16 = lane & 15;
  const int wave = tid >> 6;

  // XCD-chunked swizzle (768 % 8 == 0 -> bijective): each XCD owns 8 contiguous row-panels
  int lin = blockIdx.x + 12 * blockIdx.y;
  lin = (lin & 7) * 96 + (lin >> 3);
  const int col0 = (lin % 12) * 128, row0 = (lin / 12) * 128;

  const int wm = (wave >> 1) * 64, wn = (wave & 1) * 64;
  const float* Af = (col0 < 256) ? x : y;

  f32x4 acc[4][4];
  #pragma unroll
  for (int i = 0; i < 4; i++)
    #pragma unroll
    for (int j = 0; j < 4; j++) acc[i][j] = fzero4();

  // per-thread A chunk geometry: row = c>>3 (coalesced 256B rows), kc = c&7
  float4 a[4][2];
  auto loadA = [&](int k0) {                 // k0 in ELEMENTS
    #pragma unroll
    for (int i = 0; i < 4; i++) {
      int c = i * 256 + tid;
      const float4* src =
          (const float4*)(Af + (size_t)(row0 + (c >> 3)) * 1024 + k0 + (c & 7) * 8);
      a[i][0] = src[0];
      a[i][1] = src[1];
    }
  };
  auto stageB = [&](u16* lB, int k0) {       // k0 in ELEMENTS
    #pragma unroll
    for (int i = 0; i < 4; i++) {
      int c = i * 256 + tid;
      glds16(wt + (size_t)(col0 + (c & 127)) * 1024 + k0 + (c >> 7) * 8, lB + c * 8);
    }
  };
  auto cvtStore = [&]() {   // cvt A regs -> swizzled ds_write (auto vmcnt wait on regs)
    #pragma unroll
    for (int i = 0; i < 4; i++) {
      int c = i * 256 + tid;
      int row = c >> 3, kc = c & 7;
      u32 w0 = cvt_pk_bf16(a[i][0].x, a[i][0].y);
      u32 w1 = cvt_pk_bf16(a[i][0].z, a[i][0].w);
      u32 w2 = cvt_pk_bf16(a[i][1].x, a[i][1].y);
      u32 w3 = cvt_pk_bf16(a[i][1].z, a[i][1].w);
      *(uint4*)(lA + kc * 1024 + ((row ^ (kc << 1)) * 8)) = make_uint4(w0, w1, w2, w3);
    }
  };
  auto compute = [&](const u16* lB) {
    #pragma unroll
    for (int kk = 0; kk < 2; kk++) {
      bf16x8 af[4], bfr[4];
      const int kc = kk * 4 + quad;
      #pragma unroll
      for (int mi = 0; mi < 4; mi++)
        af[mi] = *(const bf16x8*)(lA + kc * 1024 + (((wm + mi * 16 + l16) ^ (kc << 1)) * 8));
      #pragma unroll
      for (int ni = 0; ni < 4; ni++)
        bfr[ni] = *(const bf16x8*)(lB + (kc * 128 + wn + ni * 16 + l16) * 8);
      #pragma unroll
      for (int mi = 0; mi < 4; mi++)
        #pragma unroll
        for (int ni = 0; ni < 4; ni++)
          acc[mi][ni] = __builtin_amdgcn_mfma_f32_16x16x32_bf16(af[mi], bfr[ni], acc[mi][ni], 0, 0, 0);
    }
  };

  // prologue: A(0) regs + B(0) glds in flight
  loadA(0);
  stageB(lB0, 0);

  #pragma unroll 1
  for (int it = 0; it < 16; it += 2) {
    const int k0 = it * 64;                // ELEMENT offset of even tile
    // ---- even tile (k0), B in lB0 ----
    cvtStore();                            // waits A(k0) regs (flew during prev compute)
    __syncthreads();                       // ds_writes visible; B(k0) drained
    stageB(lB1, k0 + 64);                  // prefetch next B
    loadA(k0 + 64);                        // prefetch next A
    compute(lB0);
    __syncthreads();                       // drain lands AFTER compute -> latency hidden
    // ---- odd tile (k0+64), B in lB1 ----
    cvtStore();                            // A(k0+64) regs landed during compute above
    __syncthreads();
    if (it + 2 < 16) { stageB(lB0, k0 + 128); loadA(k0 + 128); }
    compute(lB1);
    __syncthreads();
  }

  if (col0 < 512) {
    // Q / K epilogue: direct stores, fragment-friendly layouts
    #pragma unroll
    for (int mi = 0; mi < 4; mi++)
      #pragma unroll
      for (int ni = 0; ni < 4; ni++) {
        int col = col0 + wn + ni * 16 + l16;
        float bvv = (col < 256) ? bq[col] : bk[col - 256];
        #pragma unroll
        for (int r = 0; r < 4; r++) {
          int row = row0 + wm + mi * 16 + quad * 4 + r;
          float v = acc[mi][ni][r] + bvv;
          int bb = row >> 11, ml = row & 2047;
          if (col < 256) {
            int h = col >> 5, kk2 = col & 31;
            fb[(((size_t)(bb * 8 + h)) << 16) + ml * 32 + kk2] = f2bf(v);
          } else {
            int c2 = col - 256, h = c2 >> 5, kk2 = c2 & 31;
            gb[((((size_t)(bb * 8 + h)) * 16 + (ml >> 7)) << 12)
               + (kk2 >> 3) * 1024 + (ml & 127) * 8 + (kk2 & 7)] = f2bf(v);
          }
        }
      }
  } else {
    // V epilogue: transpose through LDS, write one contiguous 32KB tile [mc][dv][8]
    const int headblk = (col0 - 512) >> 7;
    const int bb = row0 >> 11, mloc0 = row0 & 2047;
    #pragma unroll
    for (int mi = 0; mi < 4; mi++)
      #pragma unroll
      for (int ni = 0; ni < 4; ni++) {
        int col = wn + ni * 16 + l16;             // block-local dv
        int rowl = wm + mi * 16 + quad * 4;       // block-local m
        float bvv = bv[(col0 - 512) + col];
        float v0 = acc[mi][ni][0] + bvv, v1 = acc[mi][ni][1] + bvv;
        float v2 = acc[mi][ni][2] + bvv, v3 = acc[mi][ni][3] + bvv;
        *(uint2*)(ls + col * 136 + rowl) =
            make_uint2(pack_bf_trunc(v1, v0), pack_bf_trunc(v3, v2));
      }
    __syncthreads();
    u16* tb = ht + ((((size_t)(bb * 8 + headblk)) * 16 + (mloc0 >> 7)) << 14);
    #pragma unroll
    for (int i = 0; i < 8; ++i) {
      int chunk = i * 256 + tid;                  // [mc=chunk>>7][dv=chunk&127]
      *(uint4*)(tb + chunk * 8) = *(const uint4*)(ls + (chunk & 127) * 136 + (chunk >> 7) * 8);
    }
  }
}

// ---------------- flash attention: 32x32 MFMA, KVBLK=128 (round-4/7 proven), dbuf ----------------
__global__ __launch_bounds__(256, 2)
void attn_kernel(const u16* __restrict__ fb, const u16* __restrict__ gb,
                 const u16* __restrict__ ht, const float* __restrict__ x,
                 const float* __restrict__ gamma, float* __restrict__ out) {
  __shared__ __align__(16) u16 lK[2][4096];    // 2 x 8 KB : K tile [kc=4][n=128][8]
  __shared__ __align__(16) u16 lV[2][16384];   // 2 x 32 KB: V tile [mc=16][dv=128][8]
  const int tid = threadIdx.x;
  const int lane = tid & 63, wave = tid >> 6;
  const int hd = lane >> 5, l31 = lane & 31;

  // XCD-affine swizzle: hw linear id % 8 == head -> each XCD holds 4 (b,head) KV sets (2.56 MB, L2-fit)
  int lin = blockIdx.x + 16 * blockIdx.y + 128 * blockIdx.z;
  const int head = lin & 7;
  const int mblk = (lin >> 3) & 15;
  const int b = lin >> 7;
  const int m0 = mblk * 128;
  const int bh = b * 8 + head;

  const float sscale = 0.17677669529663687f * 1.4426950408889634f;  // 1/sqrt(32)*log2(e)

  // Q fragments: B-frag of mfma(K,Q): lane holds Q[m=l31][k = ks*16 + hd*8 + j]
  const int qrow = m0 + wave * 32 + l31;
  union { bf16x8 v; u16 s[8]; } q0, q1;
  {
    const u16* qp = fb + (((size_t)bh * 2048 + qrow) << 5);
    q0.v = *(const bf16x8*)(qp + hd * 8);
    q1.v = *(const bf16x8*)(qp + 16 + hd * 8);
    #pragma unroll
    for (int j = 0; j < 8; ++j) {
      q0.s[j] = f2bf(__uint_as_float((u32)q0.s[j] << 16) * sscale);
      q1.s[j] = f2bf(__uint_as_float((u32)q1.s[j] << 16) * sscale);
    }
  }

  f32x16 oacc[4];
  #pragma unroll
  for (int i = 0; i < 4; ++i) oacc[i] = fzero16();
  float lsacc[4] = {0.f, 0.f, 0.f, 0.f};       // 4 independent sum chains (static indices)

  const u16* kbase = gb + ((size_t)bh << 16);
  const u16* vbase = ht + ((size_t)bh << 18);

  auto stage = [&](int bufsel, int nt) {
    const u16* ks_ = kbase + ((size_t)nt << 12);
    const u16* vs_ = vbase + ((size_t)nt << 14);
    #pragma unroll
    for (int i = 0; i < 2; ++i) glds16(ks_ + (i * 256 + tid) * 8, &lK[bufsel][(i * 256 + tid) * 8]);
    #pragma unroll
    for (int i = 0; i < 8; ++i) glds16(vs_ + (i * 256 + tid) * 8, &lV[bufsel][(i * 256 + tid) * 8]);
  };

  // one KV-tile (128 n) compute: QK^T -> leaky -> exp2 -> pack -> permlane swap -> PV
  auto compute = [&](const u16* Kc, const u16* Vc) {
    // S^T = K·Q^T per 32-row n-tile; D: col=m=l31, row(n) = (reg&3)+8*(reg>>2)+4*hd
    u32 pk[4][8];
    #pragma unroll
    for (int nt4 = 0; nt4 < 4; ++nt4) {
      bf16x8 k0 = *(const bf16x8*)(Kc + hd * 1024 + (nt4 * 32 + l31) * 8);
      bf16x8 k1 = *(const bf16x8*)(Kc + (2 + hd) * 1024 + (nt4 * 32 + l31) * 8);
      __builtin_amdgcn_s_setprio(1);
      f32x16 s = __builtin_amdgcn_mfma_f32_32x32x16_bf16(k0, q0.v, fzero16(), 0, 0, 0);
      s = __builtin_amdgcn_mfma_f32_32x32x16_bf16(k1, q1.v, s, 0, 0, 0);
      __builtin_amdgcn_s_setprio(0);
      float p[16];
      #pragma unroll
      for (int r = 0; r < 16; ++r) {
        float sv = s[r];
        float lv = fmaxf(sv, 0.2f * sv);            // leaky-relu (scale pre-folded into Q)
        p[r] = __builtin_amdgcn_exp2f(lv);
        lsacc[r & 3] += p[r];                       // 4 parallel dependency chains
      }
      #pragma unroll
      for (int s2 = 0; s2 < 4; ++s2) {              // pack pairs (n even, n odd)
        pk[nt4][s2 * 2 + 0] = pack_bf_trunc(p[s2 * 4 + 1], p[s2 * 4 + 0]);
        pk[nt4][s2 * 2 + 1] = pack_bf_trunc(p[s2 * 4 + 3], p[s2 * 4 + 2]);
      }
    }

    // PV: A-frag P[m=l31][n = kt*16 + hd*8 + j] assembled via v_permlane32_swap_b32 (T12)
    #pragma unroll
    for (int kt = 0; kt < 8; ++kt) {
      const int nt4 = kt >> 1, a = kt & 1;
      u32 w0 = pk[nt4][a * 4 + 0], w1 = pk[nt4][a * 4 + 1];   // s2=2a   pairs (rows 16a+4hd+{0..3})
      u32 w2 = pk[nt4][a * 4 + 2], w3 = pk[nt4][a * 4 + 3];   // s2=2a+1 pairs (rows 16a+8+4hd+{0..3})
      // after swap: w0/w1 = frag words 0/1 (n=16a+8hd+{0..3}), w2/w3 = words 2/3 (+4..7)
      asm("v_permlane32_swap_b32 %0, %1" : "+v"(w0), "+v"(w2));
      asm("v_permlane32_swap_b32 %0, %1" : "+v"(w1), "+v"(w3));
      union { u32 w[4]; bf16x8 v; } pf;
      pf.w[0] = w0; pf.w[1] = w1; pf.w[2] = w2; pf.w[3] = w3;
      __builtin_amdgcn_s_setprio(1);
      #pragma unroll
      for (int dvt = 0; dvt < 4; ++dvt) {
        bf16x8 vf = *(const bf16x8*)(Vc + (kt * 2 + hd) * 1024 + (dvt * 32 + l31) * 8);
        oacc[dvt] = __builtin_amdgcn_mfma_f32_32x32x16_bf16(pf.v, vf, oacc[dvt], 0, 0, 0);
      }
      __builtin_amdgcn_s_setprio(0);
    }
  };

  stage(0, 0);
  __syncthreads();

  #pragma unroll 1
  for (int it = 0; it < 16; it += 2) {
    stage(1, it + 1);                  // prefetch odd tile; drained by barrier below
    compute(&lK[0][0], &lV[0][0]);
    __syncthreads();                   // prefetch landed; buf1 ready
    if (it + 2 < 16) stage(0, it + 2); // prefetch next even tile
    compute(&lK[1][0], &lV[1][0]);
    __syncthreads();
  }

  // row sums: lane holds partial over its n-subset for row m=l31; partner holds the rest
  float lsum = (lsacc[0] + lsacc[1]) + (lsacc[2] + lsacc[3]);
  float ltot = lsum + __shfl_xor(lsum, 32, 64);
  float inv = 1.0f / ltot;
  const float gam = gamma[0];
  const size_t rowbase = ((size_t)(b * 2048 + m0 + wave * 32)) * 1024 + head * 128 + l31;
  #pragma unroll
  for (int reg = 0; reg < 16; ++reg) {
    const int m32 = (reg & 3) + 8 * (reg >> 2) + 4 * hd;
    float iv = __shfl(inv, m32, 64);
    #pragma unroll
    for (int dvt = 0; dvt < 4; ++dvt) {
      size_t idx = rowbase + (size_t)m32 * 1024 + dvt * 32;
      out[idx] = gam * (oacc[dvt][reg] * iv) + x[idx];
    }
  }
}

extern "C" void kernel_launch(void* const* d_in, const int* in_sizes, int n_in,
                              void* d_out, int out_size, void* d_ws, size_t ws_size,
                              hipStream_t stream) {
  const float* x     = (const float*)d_in[0];
  const float* y     = (const float*)d_in[1];
  const float* Wq    = (const float*)d_in[2];
  const float* bq    = (const float*)d_in[3];
  const float* Wk    = (const float*)d_in[4];
  const float* bk    = (const float*)d_in[5];
  const float* Wv    = (const float*)d_in[6];
  const float* bv    = (const float*)d_in[7];
  const float* gamma = (const float*)d_in[8];
  float* out = (float*)d_out;

  char* ws = (char*)d_ws;
  u16* wt = (u16*)(ws + 33554432);      // 3 MB   [1536][1024]  (Wq^T|Wk^T|Wv^T)
  u16* fb = (u16*)(ws + 36700160);      // 4 MB   Q  [b][h][m][32]
  u16* gb = (u16*)(ws + 40894464);      // 4 MB   K  [b][h][nt][kc][128][8]
  u16* ht = (u16*)(ws + 45088768);      // 16 MB  V  [b][h][nt][mc][128][8]

  prep_w_kernel<<<1536, 256, 0, stream>>>(Wq, Wk, Wv, wt);
  gemm_all_kernel<<<dim3(12, 64), 256, 0, stream>>>(x, y, wt, bq, bk, bv, fb, gb, ht);
  attn_kernel<<<dim3(16, 8, 4), 256, 0, stream>>>(fb, gb, ht, x, gamma, out);
}

// Round 12
// 223.648 us; speedup vs baseline: 1.1090x; 1.1090x over previous
//
#include <hip/hip_runtime.h>
#include <cstdint>
#include <cstddef>

typedef unsigned short u16;
typedef unsigned int u32;
typedef __attribute__((ext_vector_type(8))) short bf16x8;
typedef __attribute__((ext_vector_type(4))) float f32x4;
typedef __attribute__((ext_vector_type(16))) float f32x16;

__device__ __forceinline__ u16 f2bf(float f) {
  union { float f; unsigned int u; } v; v.f = f;
  unsigned int r = v.u + 0x7fffu + ((v.u >> 16) & 1u);
  return (u16)(r >> 16);
}

__device__ __forceinline__ u32 pack_bf_trunc(float hi, float lo) {
#if __has_builtin(__builtin_amdgcn_perm)
  return __builtin_amdgcn_perm(__float_as_uint(hi), __float_as_uint(lo), 0x07060302u);
#else
  return (__float_as_uint(hi) & 0xffff0000u) | (__float_as_uint(lo) >> 16);
#endif
}

__device__ __forceinline__ u32 cvt_pk_bf16(float lo, float hi) {
  u32 r;
  asm("v_cvt_pk_bf16_f32 %0, %1, %2" : "=v"(r) : "v"(lo), "v"(hi));
  return r;   // .lo16 = bf16(lo), .hi16 = bf16(hi), RNE — matches f2bf
}

__device__ __forceinline__ void glds16(const void* g, void* l) {
  __builtin_amdgcn_global_load_lds(
      (const __attribute__((address_space(1))) unsigned int*)g,
      (__attribute__((address_space(3))) unsigned int*)l, 16, 0, 0);
}

__device__ __forceinline__ f32x4 fzero4() { f32x4 z = {0.f, 0.f, 0.f, 0.f}; return z; }
__device__ __forceinline__ f32x16 fzero16() {
  f32x16 z;
  #pragma unroll
  for (int i = 0; i < 16; ++i) z[i] = 0.f;
  return z;
}

// ---------------- prep: transpose-convert weights only (x/y cvt folded into gemm) ----------------
__global__ __launch_bounds__(256)
void prep_w_kernel(const float* __restrict__ Wq, const float* __restrict__ Wk,
                   const float* __restrict__ Wv, u16* __restrict__ wt) {
  __shared__ float tile[32][33];
  int t = blockIdx.x;                       // 0..1535
  const float* in; u16* out; int N, tn;
  if (t < 256)      { in = Wq; out = wt;              N = 256;  tn = t; }
  else if (t < 512) { in = Wk; out = wt + 256 * 1024; N = 256;  tn = t - 256; }
  else              { in = Wv; out = wt + 512 * 1024; N = 1024; tn = t - 512; }
  int ntiles = N >> 5;
  int n0 = (tn % ntiles) * 32, k0 = (tn / ntiles) * 32;
  int tx = threadIdx.x & 31, ty = threadIdx.x >> 5;
  #pragma unroll
  for (int j = ty; j < 32; j += 8) tile[j][tx] = in[(size_t)(k0 + j) * N + n0 + tx];
  __syncthreads();
  #pragma unroll
  for (int j = ty; j < 32; j += 8) out[(size_t)(n0 + j) * 1024 + k0 + tx] = f2bf(tile[tx][j]);
}

// ---------------- fused projection GEMM (BK=64, A-reg pipeline, 3 blocks/CU) ------
// r9-proven structure (72.1 us): A(k+1) loads issued BEFORE the pre-compute barrier so
// their latency drains MERGED with B(k)'s glds wait (not serial). Single-buffer LDS.
// r11's dbuf-B variant spilled the A regs to scratch (+40MB HBM) -> reverted.
// out tiles over [8192][1536]: cols 0-255 -> fb (Q), 256-511 -> gb (K), 512-1535 -> ht (V).
__global__ __launch_bounds__(256, 3)
void gemm_all_kernel(const float* __restrict__ x, const float* __restrict__ y,
                     const u16* __restrict__ wt,
                     const float* __restrict__ bq, const float* __restrict__ bk,
                     const float* __restrict__ bv,
                     u16* __restrict__ fb, u16* __restrict__ gb, u16* __restrict__ ht) {
  __shared__ __align__(16) u16 ls[17408];   // 34.8 KB: staging (32 KB) / transpose (34.8 KB)
  u16* lA = ls;          // 8192 u16: A tile [kc=8][row=128][8] bf16, rows XOR-swizzled
  u16* lB = ls + 8192;   // 8192 u16: B tile [kc=8][col=128][8]
  const int tid = threadIdx.x, lane = tid & 63;
  const int quad = lane >> 4, l16 = lane & 15;
  const int wave = tid >> 6;

  // XCD-chunked swizzle (768 % 8 == 0 -> bijective): each XCD owns 8 contiguous row-panels
  int lin = blockIdx.x + 12 * blockIdx.y;
  lin = (lin & 7) * 96 + (lin >> 3);
  const int col0 = (lin % 12) * 128, row0 = (lin / 12) * 128;

  const int wm = (wave >> 1) * 64, wn = (wave & 1) * 64;
  const float* Af = (col0 < 256) ? x : y;

  f32x4 acc[4][4];
  #pragma unroll
  for (int i = 0; i < 4; i++)
    #pragma unroll
    for (int j = 0; j < 4; j++) acc[i][j] = fzero4();

  // per-thread A chunk geometry: row = c>>3 (coalesced 256B rows), kc = c&7
  float4 a[4][2];
  #pragma unroll
  for (int i = 0; i < 4; i++) {              // prologue: A(0) -> regs
    int c = i * 256 + tid;
    const float4* src = (const float4*)(Af + (size_t)(row0 + (c >> 3)) * 1024 + (c & 7) * 8);
    a[i][0] = src[0];
    a[i][1] = src[1];
  }

  for (int k0 = 0; k0 < 1024; k0 += 64) {
    __syncthreads();                         // previous compute done reading lA/lB
    // A(k0): cvt from regs + swizzled ds_write (regs landed during previous compute)
    #pragma unroll
    for (int i = 0; i < 4; i++) {
      int c = i * 256 + tid;
      int row = c >> 3, kc = c & 7;
      u32 w0 = cvt_pk_bf16(a[i][0].x, a[i][0].y);
      u32 w1 = cvt_pk_bf16(a[i][0].z, a[i][0].w);
      u32 w2 = cvt_pk_bf16(a[i][1].x, a[i][1].y);
      u32 w3 = cvt_pk_bf16(a[i][1].z, a[i][1].w);
      *(uint4*)(lA + kc * 1024 + ((row ^ (kc << 1)) * 8)) = make_uint4(w0, w1, w2, w3);
    }
    // B(k0): async global->LDS (bf16 weights, fragment-ordered)
    #pragma unroll
    for (int i = 0; i < 4; i++) {
      int c = i * 256 + tid;
      glds16(wt + (size_t)(col0 + (c & 127)) * 1024 + k0 + (c >> 7) * 8, lB + c * 8);
    }
    // A(k0+64) prefetch -> regs; drains together with B at the barrier below
    if (k0 < 960) {
      #pragma unroll
      for (int i = 0; i < 4; i++) {
        int c = i * 256 + tid;
        const float4* src =
            (const float4*)(Af + (size_t)(row0 + (c >> 3)) * 1024 + (k0 + 64) + (c & 7) * 8);
        a[i][0] = src[0];
        a[i][1] = src[1];
      }
    }
    __syncthreads();                         // drains B glds + A prefetch + ds_writes
    #pragma unroll
    for (int kk = 0; kk < 2; kk++) {
      bf16x8 af[4], bfr[4];
      const int kc = kk * 4 + quad;
      #pragma unroll
      for (int mi = 0; mi < 4; mi++)
        af[mi] = *(const bf16x8*)(lA + kc * 1024 + (((wm + mi * 16 + l16) ^ (kc << 1)) * 8));
      #pragma unroll
      for (int ni = 0; ni < 4; ni++)
        bfr[ni] = *(const bf16x8*)(lB + (kc * 128 + wn + ni * 16 + l16) * 8);
      #pragma unroll
      for (int mi = 0; mi < 4; mi++)
        #pragma unroll
        for (int ni = 0; ni < 4; ni++)
          acc[mi][ni] = __builtin_amdgcn_mfma_f32_16x16x32_bf16(af[mi], bfr[ni], acc[mi][ni], 0, 0, 0);
    }
  }

  if (col0 < 512) {
    // Q / K epilogue: direct stores, fragment-friendly layouts
    #pragma unroll
    for (int mi = 0; mi < 4; mi++)
      #pragma unroll
      for (int ni = 0; ni < 4; ni++) {
        int col = col0 + wn + ni * 16 + l16;
        float bvv = (col < 256) ? bq[col] : bk[col - 256];
        #pragma unroll
        for (int r = 0; r < 4; r++) {
          int row = row0 + wm + mi * 16 + quad * 4 + r;
          float v = acc[mi][ni][r] + bvv;
          int bb = row >> 11, ml = row & 2047;
          if (col < 256) {
            int h = col >> 5, kk2 = col & 31;
            fb[(((size_t)(bb * 8 + h)) << 16) + ml * 32 + kk2] = f2bf(v);
          } else {
            int c2 = col - 256, h = c2 >> 5, kk2 = c2 & 31;
            gb[((((size_t)(bb * 8 + h)) * 16 + (ml >> 7)) << 12)
               + (kk2 >> 3) * 1024 + (ml & 127) * 8 + (kk2 & 7)] = f2bf(v);
          }
        }
      }
  } else {
    // V epilogue: transpose through LDS, write one contiguous 32KB tile [mc][dv][8]
    const int headblk = (col0 - 512) >> 7;
    const int bb = row0 >> 11, mloc0 = row0 & 2047;
    __syncthreads();  // staging reads done; reuse ls
    #pragma unroll
    for (int mi = 0; mi < 4; mi++)
      #pragma unroll
      for (int ni = 0; ni < 4; ni++) {
        int col = wn + ni * 16 + l16;             // block-local dv
        int rowl = wm + mi * 16 + quad * 4;       // block-local m
        float bvv = bv[(col0 - 512) + col];
        float v0 = acc[mi][ni][0] + bvv, v1 = acc[mi][ni][1] + bvv;
        float v2 = acc[mi][ni][2] + bvv, v3 = acc[mi][ni][3] + bvv;
        *(uint2*)(ls + col * 136 + rowl) =
            make_uint2(pack_bf_trunc(v1, v0), pack_bf_trunc(v3, v2));
      }
    __syncthreads();
    u16* tb = ht + ((((size_t)(bb * 8 + headblk)) * 16 + (mloc0 >> 7)) << 14);
    #pragma unroll
    for (int i = 0; i < 8; ++i) {
      int chunk = i * 256 + tid;                  // [mc=chunk>>7][dv=chunk&127]
      *(uint4*)(tb + chunk * 8) = *(const uint4*)(ls + (chunk & 127) * 136 + (chunk >> 7) * 8);
    }
  }
}

// ---------------- flash attention: 32x32 MFMA, KVBLK=128 (proven), dbuf ----------------
__global__ __launch_bounds__(256, 2)
void attn_kernel(const u16* __restrict__ fb, const u16* __restrict__ gb,
                 const u16* __restrict__ ht, const float* __restrict__ x,
                 const float* __restrict__ gamma, float* __restrict__ out) {
  __shared__ __align__(16) u16 lK[2][4096];    // 2 x 8 KB : K tile [kc=4][n=128][8]
  __shared__ __align__(16) u16 lV[2][16384];   // 2 x 32 KB: V tile [mc=16][dv=128][8]
  const int tid = threadIdx.x;
  const int lane = tid & 63, wave = tid >> 6;
  const int hd = lane >> 5, l31 = lane & 31;

  // XCD-affine swizzle: hw linear id % 8 == head -> each XCD holds 4 (b,head) KV sets (2.56 MB, L2-fit)
  int lin = blockIdx.x + 16 * blockIdx.y + 128 * blockIdx.z;
  const int head = lin & 7;
  const int mblk = (lin >> 3) & 15;
  const int b = lin >> 7;
  const int m0 = mblk * 128;
  const int bh = b * 8 + head;

  const float sscale = 0.17677669529663687f * 1.4426950408889634f;  // 1/sqrt(32)*log2(e)

  // Q fragments: B-frag of mfma(K,Q): lane holds Q[m=l31][k = ks*16 + hd*8 + j]
  const int qrow = m0 + wave * 32 + l31;
  union { bf16x8 v; u16 s[8]; } q0, q1;
  {
    const u16* qp = fb + (((size_t)bh * 2048 + qrow) << 5);
    q0.v = *(const bf16x8*)(qp + hd * 8);
    q1.v = *(const bf16x8*)(qp + 16 + hd * 8);
    #pragma unroll
    for (int j = 0; j < 8; ++j) {
      q0.s[j] = f2bf(__uint_as_float((u32)q0.s[j] << 16) * sscale);
      q1.s[j] = f2bf(__uint_as_float((u32)q1.s[j] << 16) * sscale);
    }
  }

  f32x16 oacc[4];
  #pragma unroll
  for (int i = 0; i < 4; ++i) oacc[i] = fzero16();
  const f32x16 zc = fzero16();                 // hoisted QK^T C-init (kernel-lifetime constant)
  float lsacc[4] = {0.f, 0.f, 0.f, 0.f};       // 4 independent sum chains (static indices)

  const u16* kbase = gb + ((size_t)bh << 16);
  const u16* vbase = ht + ((size_t)bh << 18);

  auto stage = [&](int bufsel, int nt) {
    const u16* ks_ = kbase + ((size_t)nt << 12);
    const u16* vs_ = vbase + ((size_t)nt << 14);
    #pragma unroll
    for (int i = 0; i < 2; ++i) glds16(ks_ + (i * 256 + tid) * 8, &lK[bufsel][(i * 256 + tid) * 8]);
    #pragma unroll
    for (int i = 0; i < 8; ++i) glds16(vs_ + (i * 256 + tid) * 8, &lV[bufsel][(i * 256 + tid) * 8]);
  };

  // one KV-tile (128 n) compute: QK^T -> leaky -> exp2 -> pack -> permlane swap -> PV
  auto compute = [&](const u16* Kc, const u16* Vc) {
    // S^T = K·Q^T per 32-row n-tile; D: col=m=l31, row(n) = (reg&3)+8*(reg>>2)+4*hd
    u32 pk[4][8];
    #pragma unroll
    for (int nt4 = 0; nt4 < 4; ++nt4) {
      bf16x8 k0 = *(const bf16x8*)(Kc + hd * 1024 + (nt4 * 32 + l31) * 8);
      bf16x8 k1 = *(const bf16x8*)(Kc + (2 + hd) * 1024 + (nt4 * 32 + l31) * 8);
      __builtin_amdgcn_s_setprio(1);
      f32x16 s = __builtin_amdgcn_mfma_f32_32x32x16_bf16(k0, q0.v, zc, 0, 0, 0);
      s = __builtin_amdgcn_mfma_f32_32x32x16_bf16(k1, q1.v, s, 0, 0, 0);
      __builtin_amdgcn_s_setprio(0);
      float p[16];
      #pragma unroll
      for (int r = 0; r < 16; ++r) {
        float sv = s[r];
        float lv = fmaxf(sv, 0.2f * sv);            // leaky-relu (scale pre-folded into Q)
        p[r] = __builtin_amdgcn_exp2f(lv);
        lsacc[r & 3] += p[r];                       // 4 parallel dependency chains
      }
      #pragma unroll
      for (int s2 = 0; s2 < 4; ++s2) {              // pack pairs (n even, n odd)
        pk[nt4][s2 * 2 + 0] = pack_bf_trunc(p[s2 * 4 + 1], p[s2 * 4 + 0]);
        pk[nt4][s2 * 2 + 1] = pack_bf_trunc(p[s2 * 4 + 3], p[s2 * 4 + 2]);
      }
    }

    // PV: A-frag P[m=l31][n = kt*16 + hd*8 + j] assembled via v_permlane32_swap_b32 (T12)
    #pragma unroll
    for (int kt = 0; kt < 8; ++kt) {
      const int nt4 = kt >> 1, a = kt & 1;
      u32 w0 = pk[nt4][a * 4 + 0], w1 = pk[nt4][a * 4 + 1];   // s2=2a   pairs (rows 16a+4hd+{0..3})
      u32 w2 = pk[nt4][a * 4 + 2], w3 = pk[nt4][a * 4 + 3];   // s2=2a+1 pairs (rows 16a+8+4hd+{0..3})
      // after swap: w0/w1 = frag words 0/1 (n=16a+8hd+{0..3}), w2/w3 = words 2/3 (+4..7)
      asm("v_permlane32_swap_b32 %0, %1" : "+v"(w0), "+v"(w2));
      asm("v_permlane32_swap_b32 %0, %1" : "+v"(w1), "+v"(w3));
      union { u32 w[4]; bf16x8 v; } pf;
      pf.w[0] = w0; pf.w[1] = w1; pf.w[2] = w2; pf.w[3] = w3;
      __builtin_amdgcn_s_setprio(1);
      #pragma unroll
      for (int dvt = 0; dvt < 4; ++dvt) {
        bf16x8 vf = *(const bf16x8*)(Vc + (kt * 2 + hd) * 1024 + (dvt * 32 + l31) * 8);
        oacc[dvt] = __builtin_amdgcn_mfma_f32_32x32x16_bf16(pf.v, vf, oacc[dvt], 0, 0, 0);
      }
      __builtin_amdgcn_s_setprio(0);
    }
  };

  stage(0, 0);
  __syncthreads();

  #pragma unroll 1
  for (int it = 0; it < 16; it += 2) {
    stage(1, it + 1);                  // prefetch odd tile; drained by barrier below
    compute(&lK[0][0], &lV[0][0]);
    __syncthreads();                   // prefetch landed; buf1 ready
    if (it + 2 < 16) stage(0, it + 2); // prefetch next even tile
    compute(&lK[1][0], &lV[1][0]);
    __syncthreads();
  }

  // row sums: lane holds partial over its n-subset for row m=l31; partner holds the rest
  float lsum = (lsacc[0] + lsacc[1]) + (lsacc[2] + lsacc[3]);
  float ltot = lsum + __shfl_xor(lsum, 32, 64);
  float inv = 1.0f / ltot;
  const float gam = gamma[0];
  const size_t rowbase = ((size_t)(b * 2048 + m0 + wave * 32)) * 1024 + head * 128 + l31;
  #pragma unroll
  for (int reg = 0; reg < 16; ++reg) {
    const int m32 = (reg & 3) + 8 * (reg >> 2) + 4 * hd;
    float iv = __shfl(inv, m32, 64);
    #pragma unroll
    for (int dvt = 0; dvt < 4; ++dvt) {
      size_t idx = rowbase + (size_t)m32 * 1024 + dvt * 32;
      out[idx] = gam * (oacc[dvt][reg] * iv) + x[idx];
    }
  }
}

extern "C" void kernel_launch(void* const* d_in, const int* in_sizes, int n_in,
                              void* d_out, int out_size, void* d_ws, size_t ws_size,
                              hipStream_t stream) {
  const float* x     = (const float*)d_in[0];
  const float* y     = (const float*)d_in[1];
  const float* Wq    = (const float*)d_in[2];
  const float* bq    = (const float*)d_in[3];
  const float* Wk    = (const float*)d_in[4];
  const float* bk    = (const float*)d_in[5];
  const float* Wv    = (const float*)d_in[6];
  const float* bv    = (const float*)d_in[7];
  const float* gamma = (const float*)d_in[8];
  float* out = (float*)d_out;

  char* ws = (char*)d_ws;
  u16* wt = (u16*)(ws + 33554432);      // 3 MB   [1536][1024]  (Wq^T|Wk^T|Wv^T)
  u16* fb = (u16*)(ws + 36700160);      // 4 MB   Q  [b][h][m][32]
  u16* gb = (u16*)(ws + 40894464);      // 4 MB   K  [b][h][nt][kc][128][8]
  u16* ht = (u16*)(ws + 45088768);      // 16 MB  V  [b][h][nt][mc][128][8]

  prep_w_kernel<<<1536, 256, 0, stream>>>(Wq, Wk, Wv, wt);
  gemm_all_kernel<<<dim3(12, 64), 256, 0, stream>>>(x, y, wt, bq, bk, bv, fb, gb, ht);
  attn_kernel<<<dim3(16, 8, 4), 256, 0, stream>>>(fb, gb, ht, x, gamma, out);
}